// Round 1
// baseline (9991.507 us; speedup 1.0000x reference)
//
#include <hip/hip_runtime.h>
#include <cmath>

#define B_ 32
#define S_ 128
#define T_ 64
#define STEPS_ 63
#define V_ 32000
#define E_ 512
#define H_ 512
#define G3 1536  // 3*H

// ---------------- transpose: src[R][C] -> dst[C][R] ----------------
__global__ void k_transpose(const float* __restrict__ src, float* __restrict__ dst,
                            int R, int C) {
  __shared__ float tile[32][33];
  int c0 = blockIdx.x * 32, r0 = blockIdx.y * 32;
  int tx = threadIdx.x, ty = threadIdx.y;  // (32, 8)
#pragma unroll
  for (int i = 0; i < 32; i += 8) {
    int r = r0 + ty + i, c = c0 + tx;
    if (r < R && c < C) tile[ty + i][tx] = src[(long)r * C + c];
  }
  __syncthreads();
#pragma unroll
  for (int i = 0; i < 32; i += 8) {
    int c = c0 + ty + i, r = r0 + tx;
    if (r < R && c < C) dst[(long)c * R + r] = tile[tx][ty + i];
  }
}

// ---------------- tiled f32 GEMM: C[m,n] = Arow(m)[k] * Bt[k][n] + bias[n] ----
// amode: 0 dense A[M][K]; 1 gather emb rows via src tokens (m = s*32+b);
//        2 gather emb rows via tgt tokens (m = t*32+b)
// out address = (m%32)*sb + (m/32)*st + n   (B_=32 hard-coded)
__global__ __launch_bounds__(256) void k_gemm(
    const float* __restrict__ A, const float* __restrict__ emb,
    const int* __restrict__ tok, int amode,
    const float* __restrict__ Bt, int ldb,
    const float* __restrict__ bias,
    float* __restrict__ out, long sb, long st,
    int M, int N, int K) {
  __shared__ float As[16][68];
  __shared__ float Bs[16][68];
  int t = threadIdx.x;
  int n0 = blockIdx.x * 64, m0 = blockIdx.y * 64;
  int tx = t & 15, ty = t >> 4;
  int la_r = t >> 2, la_c = (t & 3) * 4;       // A tile load: row, k-offset
  int lb_k = t >> 4, lb_n = (t & 15) * 4;      // B tile load
  float acc[4][4] = {};

  int gm = m0 + la_r;
  int gmc = gm < M ? gm : M - 1;
  const float* arow;
  if (amode == 0) {
    arow = A + (long)gmc * K;
  } else {
    int b = gmc & 31, q = gmc >> 5;
    int token = (amode == 1) ? tok[b * S_ + q] : tok[b * T_ + q];
    arow = emb + (long)token * K;
  }
  const float* brow = Bt + (long)lb_k * ldb + n0 + lb_n;

  for (int k0 = 0; k0 < K; k0 += 16) {
    float4 av = *(const float4*)(arow + k0 + la_c);
    As[la_c + 0][la_r] = av.x;
    As[la_c + 1][la_r] = av.y;
    As[la_c + 2][la_r] = av.z;
    As[la_c + 3][la_r] = av.w;
    float4 bv = *(const float4*)(brow + (long)k0 * ldb);
    *(float4*)&Bs[lb_k][lb_n] = bv;
    __syncthreads();
#pragma unroll
    for (int kk = 0; kk < 16; ++kk) {
      float4 a = *(const float4*)&As[kk][ty * 4];
      float4 b = *(const float4*)&Bs[kk][tx * 4];
      acc[0][0] += a.x * b.x; acc[0][1] += a.x * b.y; acc[0][2] += a.x * b.z; acc[0][3] += a.x * b.w;
      acc[1][0] += a.y * b.x; acc[1][1] += a.y * b.y; acc[1][2] += a.y * b.z; acc[1][3] += a.y * b.w;
      acc[2][0] += a.z * b.x; acc[2][1] += a.z * b.y; acc[2][2] += a.z * b.z; acc[2][3] += a.z * b.w;
      acc[3][0] += a.w * b.x; acc[3][1] += a.w * b.y; acc[3][2] += a.w * b.z; acc[3][3] += a.w * b.w;
    }
    __syncthreads();
  }
#pragma unroll
  for (int i = 0; i < 4; ++i) {
    int m = m0 + ty * 4 + i;
    if (m >= M) continue;
    long base = (long)(m & 31) * sb + (long)(m >> 5) * st;
#pragma unroll
    for (int j = 0; j < 4; ++j) {
      int n = n0 + tx * 4 + j;
      out[base + n] = acc[i][j] + bias[n];
    }
  }
}

// ---------------- encoder recurrent step ----------------
// grid 64 blocks = 8 j-tiles x 8 b-tiles; block 256 = 64 j x 4 b
__global__ __launch_bounds__(256) void k_enc_step(
    const float* __restrict__ gi_all,  // [S*B][1536], row = s*32+b (bih folded)
    const float* __restrict__ WhhT,    // [512][1536]
    const float* __restrict__ bhh,
    const int* __restrict__ lens,
    const float* __restrict__ h_in,    // [32][512]
    float* __restrict__ h_out,
    float* __restrict__ EO,            // enc_outs [32][128][512]
    int s) {
  __shared__ float hs[2048];
  int t = threadIdx.x;
  int j0 = (blockIdx.x & 7) * 64;
  int b0 = (blockIdx.x >> 3) * 4;
  const float4* h4 = (const float4*)(h_in + b0 * 512);
  for (int i = t; i < 512; i += 256) ((float4*)hs)[i] = h4[i];
  __syncthreads();
  int tj = t & 63, tb = t >> 6;
  int j = j0 + tj, b = b0 + tb;
  const float* hr = hs + tb * 512;
  float ar = bhh[j], az = bhh[512 + j], an = bhh[1024 + j];
  for (int k = 0; k < 512; k += 4) {
    float4 hk = *(const float4*)(hr + k);
    const float* w = WhhT + (long)k * 1536;
    ar += hk.x * w[j];        az += hk.x * w[512 + j];  an += hk.x * w[1024 + j];
    ar += hk.y * w[1536 + j]; az += hk.y * w[2048 + j]; an += hk.y * w[2560 + j];
    ar += hk.z * w[3072 + j]; az += hk.z * w[3584 + j]; an += hk.z * w[4096 + j];
    ar += hk.w * w[4608 + j]; az += hk.w * w[5120 + j]; an += hk.w * w[5632 + j];
  }
  const float* gi = gi_all + ((long)s * 32 + b) * 1536;
  float r = 1.f / (1.f + expf(-(gi[j] + ar)));
  float z = 1.f / (1.f + expf(-(gi[512 + j] + az)));
  float n = tanhf(gi[1024 + j] + r * an);
  float hold = hr[j];
  float hnew = (1.f - z) * n + z * hold;
  bool valid = s < lens[b];
  h_out[b * 512 + j] = valid ? hnew : hold;
  EO[((long)b * 128 + s) * 512 + j] = valid ? hnew : 0.f;
}

// ---------------- decoder attention ----------------
// grid 32 blocks (one per b); block 256
__global__ __launch_bounds__(256) void k_dec_att(
    const float* __restrict__ EO, const float* __restrict__ h,
    const int* __restrict__ lens,
    float* __restrict__ ctx, float* __restrict__ attns, int tstep) {
  __shared__ float hsv[512];
  __shared__ float sc[128];
  __shared__ float wred[8];
  int b = blockIdx.x;
  int t = threadIdx.x;
  int lane = t & 63, wave = t >> 6;
  for (int i = t; i < 128; i += 256) ((float4*)hsv)[i] = ((const float4*)(h + b * 512))[i];
  __syncthreads();
  float4 h1 = ((const float4*)hsv)[lane * 2];
  float4 h2 = ((const float4*)hsv)[lane * 2 + 1];
  for (int si = 0; si < 32; ++si) {
    int s = wave * 32 + si;
    const float4* er = (const float4*)(EO + ((long)b * 128 + s) * 512);
    float4 e1 = er[lane * 2], e2 = er[lane * 2 + 1];
    float p = e1.x * h1.x + e1.y * h1.y + e1.z * h1.z + e1.w * h1.w +
              e2.x * h2.x + e2.y * h2.y + e2.z * h2.z + e2.w * h2.w;
#pragma unroll
    for (int off = 32; off > 0; off >>= 1) p += __shfl_down(p, off, 64);
    if (lane == 0) sc[s] = p;
  }
  __syncthreads();
  int len = lens[b];
  float v = (t < 128) ? ((t < len) ? sc[t] : -INFINITY) : -INFINITY;
  float wm = v;
#pragma unroll
  for (int off = 32; off > 0; off >>= 1) wm = fmaxf(wm, __shfl_down(wm, off, 64));
  if (lane == 0) wred[wave] = wm;
  __syncthreads();
  float m = fmaxf(fmaxf(wred[0], wred[1]), fmaxf(wred[2], wred[3]));
  float e = (t < 128 && t < len) ? expf(sc[t] - m) : 0.f;
  float wsum = e;
#pragma unroll
  for (int off = 32; off > 0; off >>= 1) wsum += __shfl_down(wsum, off, 64);
  if (lane == 0) wred[4 + wave] = wsum;
  __syncthreads();
  float ssum = wred[4] + wred[5] + wred[6] + wred[7];
  float aw = e / ssum;
  if (t < 128) {
    sc[t] = aw;
    attns[((long)b * STEPS_ + tstep) * 128 + t] = aw;
  }
  __syncthreads();
  for (int j = t; j < 512; j += 256) {
    float acc = 0.f;
    for (int s = 0; s < 128; ++s) acc += sc[s] * EO[((long)b * 128 + s) * 512 + j];
    ctx[b * 512 + j] = acc;
  }
}

// ---------------- decoder GRU cell ----------------
// grid 64 blocks = 8 j-tiles x 8 b-tiles; block 256 = 64 j x 4 b
__global__ __launch_bounds__(256) void k_dec_cell(
    const float* __restrict__ gie,   // [STEPS*B][1536], row = t*32+b (e-part + bih)
    const float* __restrict__ ctx,   // [32][512]
    const float* __restrict__ WihT,  // [1024][1536], ctx part = rows 512..1023
    const float* __restrict__ WhhT,  // [512][1536]
    const float* __restrict__ bhh,
    const float* __restrict__ h_in, float* __restrict__ h_out, int tstep) {
  __shared__ float hs[2048];
  __shared__ float cs[2048];
  int t = threadIdx.x;
  int j0 = (blockIdx.x & 7) * 64;
  int b0 = (blockIdx.x >> 3) * 4;
  const float4* h4 = (const float4*)(h_in + b0 * 512);
  const float4* c4 = (const float4*)(ctx + b0 * 512);
  for (int i = t; i < 512; i += 256) { ((float4*)hs)[i] = h4[i]; ((float4*)cs)[i] = c4[i]; }
  __syncthreads();
  int tj = t & 63, tb = t >> 6;
  int j = j0 + tj, b = b0 + tb;
  const float* hr = hs + tb * 512;
  const float* cr = cs + tb * 512;
  float ar = bhh[j], az = bhh[512 + j], an = bhh[1024 + j];
  float gr = 0.f, gz = 0.f, gn = 0.f;
  for (int k = 0; k < 512; k += 4) {
    float4 hk = *(const float4*)(hr + k);
    float4 ck = *(const float4*)(cr + k);
    const float* wh = WhhT + (long)k * 1536;
    const float* wc = WihT + (long)(512 + k) * 1536;
    ar += hk.x * wh[j];        az += hk.x * wh[512 + j];  an += hk.x * wh[1024 + j];
    ar += hk.y * wh[1536 + j]; az += hk.y * wh[2048 + j]; an += hk.y * wh[2560 + j];
    ar += hk.z * wh[3072 + j]; az += hk.z * wh[3584 + j]; an += hk.z * wh[4096 + j];
    ar += hk.w * wh[4608 + j]; az += hk.w * wh[5120 + j]; an += hk.w * wh[5632 + j];
    gr += ck.x * wc[j];        gz += ck.x * wc[512 + j];  gn += ck.x * wc[1024 + j];
    gr += ck.y * wc[1536 + j]; gz += ck.y * wc[2048 + j]; gn += ck.y * wc[2560 + j];
    gr += ck.z * wc[3072 + j]; gz += ck.z * wc[3584 + j]; gn += ck.z * wc[4096 + j];
    gr += ck.w * wc[4608 + j]; gz += ck.w * wc[5120 + j]; gn += ck.w * wc[5632 + j];
  }
  const float* gi = gie + ((long)tstep * 32 + b) * 1536;
  float r = 1.f / (1.f + expf(-(gi[j] + gr + ar)));
  float z = 1.f / (1.f + expf(-(gi[512 + j] + gz + az)));
  float n = tanhf(gi[1024 + j] + gn + r * an);
  float hold = hr[j];
  h_out[b * 512 + j] = (1.f - z) * n + z * hold;
}

// ---------------- decoder cc = tanh([hn,ctx] @ Wc.T + bc) ----------------
__global__ __launch_bounds__(256) void k_dec_cc(
    const float* __restrict__ hn, const float* __restrict__ ctx,
    const float* __restrict__ WcT,  // [1024][512]
    const float* __restrict__ bc,
    float* __restrict__ ccall, int tstep) {
  __shared__ float hs[2048];
  __shared__ float cs[2048];
  int t = threadIdx.x;
  int i0 = (blockIdx.x & 7) * 64;
  int b0 = (blockIdx.x >> 3) * 4;
  const float4* h4 = (const float4*)(hn + b0 * 512);
  const float4* c4 = (const float4*)(ctx + b0 * 512);
  for (int i = t; i < 512; i += 256) { ((float4*)hs)[i] = h4[i]; ((float4*)cs)[i] = c4[i]; }
  __syncthreads();
  int ti = t & 63, tb = t >> 6;
  int i = i0 + ti, b = b0 + tb;
  const float* hr = hs + tb * 512;
  const float* cr = cs + tb * 512;
  float acc = bc[i];
  for (int k = 0; k < 512; k += 4) {
    float4 hk = *(const float4*)(hr + k);
    float4 ck = *(const float4*)(cr + k);
    const float* w = WcT + (long)k * 512 + i;
    const float* w2 = WcT + (long)(512 + k) * 512 + i;
    acc += hk.x * w[0];    acc += hk.y * w[512];  acc += hk.z * w[1024];  acc += hk.w * w[1536];
    acc += ck.x * w2[0];   acc += ck.y * w2[512]; acc += ck.z * w2[1024]; acc += ck.w * w2[1536];
  }
  ccall[((long)tstep * 32 + b) * 512 + i] = tanhf(acc);
}

extern "C" void kernel_launch(void* const* d_in, const int* in_sizes, int n_in,
                              void* d_out, int out_size, void* d_ws, size_t ws_size,
                              hipStream_t stream) {
  (void)in_sizes; (void)n_in; (void)out_size; (void)ws_size;
  const int*   src   = (const int*)d_in[0];
  const int*   lens  = (const int*)d_in[1];
  const int*   tgt   = (const int*)d_in[2];
  const float* emb_e = (const float*)d_in[3];
  const float* Wih_e = (const float*)d_in[4];
  const float* Whh_e = (const float*)d_in[5];
  const float* bih_e = (const float*)d_in[6];
  const float* bhh_e = (const float*)d_in[7];
  const float* emb_d = (const float*)d_in[8];
  const float* Wih_d = (const float*)d_in[9];
  const float* Whh_d = (const float*)d_in[10];
  const float* bih_d = (const float*)d_in[11];
  const float* bhh_d = (const float*)d_in[12];
  const float* Wc    = (const float*)d_in[13];
  const float* bc    = (const float*)d_in[14];
  const float* Wo    = (const float*)d_in[15];
  const float* bo    = (const float*)d_in[16];

  float* logits = (float*)d_out;
  float* attns  = (float*)d_out + (long)B_ * STEPS_ * V_;

  float* w = (float*)d_ws;
  float* WihT_e = w;                   // 512 x 1536
  float* WhhT_e = WihT_e + 786432;     // 512 x 1536
  float* WihT_d = WhhT_e + 786432;     // 1024 x 1536
  float* WhhT_d = WihT_d + 1572864;    // 512 x 1536
  float* WcT    = WhhT_d + 786432;     // 1024 x 512
  float* WoT    = WcT + 524288;        // 512 x 32000
  float* GIe    = WoT + 16384000;      // 4096 x 1536
  float* GId    = GIe + 6291456;       // 2016 x 1536
  float* EO     = GId + 3096576;       // 32 x 128 x 512
  float* h0     = EO + 2097152;        // 32 x 512
  float* h1     = h0 + 16384;
  float* ctx    = h1 + 16384;
  float* ccall  = ctx + 16384;         // 2016 x 512
  float* hb[2] = {h0, h1};

  dim3 tb(32, 8);
  k_transpose<<<dim3(512 / 32, 1536 / 32), tb, 0, stream>>>(Wih_e, WihT_e, 1536, 512);
  k_transpose<<<dim3(512 / 32, 1536 / 32), tb, 0, stream>>>(Whh_e, WhhT_e, 1536, 512);
  k_transpose<<<dim3(1024 / 32, 1536 / 32), tb, 0, stream>>>(Wih_d, WihT_d, 1536, 1024);
  k_transpose<<<dim3(512 / 32, 1536 / 32), tb, 0, stream>>>(Whh_d, WhhT_d, 1536, 512);
  k_transpose<<<dim3(1024 / 32, 512 / 32), tb, 0, stream>>>(Wc, WcT, 512, 1024);
  k_transpose<<<dim3(512 / 32, 32000 / 32), tb, 0, stream>>>(Wo, WoT, 32000, 512);

  // GI_enc[s*32+b][:] = emb_enc[src[b,s]] @ Wih_e^T + bih_e
  k_gemm<<<dim3(1536 / 64, 4096 / 64), 256, 0, stream>>>(
      nullptr, emb_e, src, 1, WihT_e, 1536, bih_e, GIe, 1536L, 32L * 1536L, 4096, 1536, 512);
  // GI_dec_e[t*32+b][:] = emb_dec[tgt[b,t]] @ Wih_d[:, :512]^T + bih_d
  k_gemm<<<dim3(1536 / 64, (2016 + 63) / 64), 256, 0, stream>>>(
      nullptr, emb_d, tgt, 2, WihT_d, 1536, bih_d, GId, 1536L, 32L * 1536L, 2016, 1536, 512);

  hipMemsetAsync(h0, 0, 16384 * sizeof(float), stream);

  for (int s = 0; s < S_; ++s) {
    k_enc_step<<<64, 256, 0, stream>>>(GIe, WhhT_e, bhh_e, lens, hb[s & 1], hb[(s + 1) & 1], EO, s);
  }
  // encoder ends with final h in hb[0] (128 steps)

  for (int t = 0; t < STEPS_; ++t) {
    k_dec_att<<<32, 256, 0, stream>>>(EO, hb[t & 1], lens, ctx, attns, t);
    k_dec_cell<<<64, 256, 0, stream>>>(GId, ctx, WihT_d, WhhT_d, bhh_d, hb[t & 1], hb[(t + 1) & 1], t);
    k_dec_cc<<<64, 256, 0, stream>>>(hb[(t + 1) & 1], ctx, WcT, bc, ccall, t);
  }

  // logits[b, t, :] = ccall[t*32+b, :] @ Wo^T + bo  (one batched GEMM)
  k_gemm<<<dim3(32000 / 64, (2016 + 63) / 64), 256, 0, stream>>>(
      ccall, nullptr, nullptr, 0, WoT, 32000, bo, logits,
      (long)STEPS_ * V_, (long)V_, 2016, 32000, 512);
}

// Round 2
// 9225.992 us; speedup vs baseline: 1.0830x; 1.0830x over previous
//
#include <hip/hip_runtime.h>
#include <cmath>

#define B_ 32
#define S_ 128
#define T_ 64
#define STEPS_ 63
#define V_ 32000
#define E_ 512
#define H_ 512

typedef __attribute__((ext_vector_type(4))) float f32x4;
typedef __attribute__((ext_vector_type(8))) short bf16x8;

__device__ inline short f2bf(float x) {
  unsigned u = __builtin_bit_cast(unsigned, x);
  u = (u + 0x7fffu + ((u >> 16) & 1u)) >> 16;
  return (short)u;
}
__device__ inline float bf2f(short h) {
  unsigned u = ((unsigned)(unsigned short)h) << 16;
  return __builtin_bit_cast(float, u);
}

// ---------------- transpose: src[R][C] -> dst[C][R] ----------------
__global__ void k_transpose(const float* __restrict__ src, float* __restrict__ dst,
                            int R, int C) {
  __shared__ float tile[32][33];
  int c0 = blockIdx.x * 32, r0 = blockIdx.y * 32;
  int tx = threadIdx.x, ty = threadIdx.y;  // (32, 8)
#pragma unroll
  for (int i = 0; i < 32; i += 8) {
    int r = r0 + ty + i, c = c0 + tx;
    if (r < R && c < C) tile[ty + i][tx] = src[(long)r * C + c];
  }
  __syncthreads();
#pragma unroll
  for (int i = 0; i < 32; i += 8) {
    int c = c0 + ty + i, r = r0 + tx;
    if (r < R && c < C) dst[(long)c * R + r] = tile[tx][ty + i];
  }
}

// ---------------- MFMA bf16 split-precision GEMM ----------------
// C[m,n] = sum_k Arow(m)[k] * Bmat[n][k] + bias[n]
// A, B staged to LDS as bf16 hi/lo pairs; 3 MFMA products give ~f32 accuracy.
// amode: 0 dense A[M][K]; 1 gather emb rows via src tok (m=s*32+b);
//        2 gather via tgt tok (m=t*32+b).
// out addr = (m&31)*sb + (m>>5)*st + n
__global__ __launch_bounds__(256) void k_mfma_gemm(
    const float* __restrict__ A, const float* __restrict__ emb,
    const int* __restrict__ tok, int amode,
    const float* __restrict__ Bmat, long ldb,
    const float* __restrict__ bias,
    float* __restrict__ out, long sb, long st,
    int M, int N, int K) {
  // padded rows: 32 bf16 + 8 pad = 80B stride -> 2-way bank conflicts max
  __shared__ short Ah[128 * 40];
  __shared__ short Al[128 * 40];
  __shared__ short Bh[128 * 40];
  __shared__ short Bl[128 * 40];
  int t = threadIdx.x;
  int n0 = blockIdx.x * 128, m0 = blockIdx.y * 128;
  int ar = t >> 2, ac = (t & 3) * 8;  // staging: row-in-64, k-chunk(8)

  const float* arow0;
  const float* arow1;
  {
    int m = m0 + ar;       int mc = m < M ? m : M - 1;
    int m2 = m0 + ar + 64; int mc2 = m2 < M ? m2 : M - 1;
    if (amode == 0) {
      arow0 = A + (long)mc * K;
      arow1 = A + (long)mc2 * K;
    } else {
      int b = mc & 31, q = mc >> 5;
      int tk = (amode == 1) ? tok[b * S_ + q] : tok[b * T_ + q];
      arow0 = emb + (long)tk * K;
      b = mc2 & 31; q = mc2 >> 5;
      tk = (amode == 1) ? tok[b * S_ + q] : tok[b * T_ + q];
      arow1 = emb + (long)tk * K;
    }
  }
  const float* brow0 = Bmat + (long)(n0 + ar) * ldb;
  const float* brow1 = Bmat + (long)(n0 + ar + 64) * ldb;

  int lane = t & 63, wave = t >> 6;
  int wm = (wave >> 1) * 64, wn = (wave & 1) * 64;  // 2x2 wave grid, 64x64 each
  int lr = lane & 15, lk = lane >> 4;
  f32x4 acc[4][4] = {};

  for (int k0 = 0; k0 < K; k0 += 32) {
    auto stage = [&](const float* rowp, short* Dh, short* Dl, int r) {
      float4 x0 = *(const float4*)(rowp + k0 + ac);
      float4 x1 = *(const float4*)(rowp + k0 + ac + 4);
      float xs[8] = {x0.x, x0.y, x0.z, x0.w, x1.x, x1.y, x1.z, x1.w};
      bf16x8 hi, lo;
#pragma unroll
      for (int i = 0; i < 8; ++i) {
        short h = f2bf(xs[i]);
        hi[i] = h;
        lo[i] = f2bf(xs[i] - bf2f(h));
      }
      *(bf16x8*)&Dh[r * 40 + ac] = hi;
      *(bf16x8*)&Dl[r * 40 + ac] = lo;
    };
    stage(arow0, Ah, Al, ar);
    stage(arow1, Ah, Al, ar + 64);
    stage(brow0, Bh, Bl, ar);
    stage(brow1, Bh, Bl, ar + 64);
    __syncthreads();

    bf16x8 a_h[4], a_l[4], b_h[4], b_l[4];
#pragma unroll
    for (int i = 0; i < 4; ++i) {
      int ra = (wm + i * 16 + lr) * 40 + lk * 8;
      a_h[i] = *(const bf16x8*)&Ah[ra];
      a_l[i] = *(const bf16x8*)&Al[ra];
      int rb = (wn + i * 16 + lr) * 40 + lk * 8;
      b_h[i] = *(const bf16x8*)&Bh[rb];
      b_l[i] = *(const bf16x8*)&Bl[rb];
    }
#pragma unroll
    for (int i = 0; i < 4; ++i)
#pragma unroll
      for (int j = 0; j < 4; ++j) {
        acc[i][j] = __builtin_amdgcn_mfma_f32_16x16x32_bf16(a_l[i], b_h[j], acc[i][j], 0, 0, 0);
        acc[i][j] = __builtin_amdgcn_mfma_f32_16x16x32_bf16(a_h[i], b_l[j], acc[i][j], 0, 0, 0);
        acc[i][j] = __builtin_amdgcn_mfma_f32_16x16x32_bf16(a_h[i], b_h[j], acc[i][j], 0, 0, 0);
      }
    __syncthreads();
  }

#pragma unroll
  for (int i = 0; i < 4; ++i) {
#pragma unroll
    for (int r = 0; r < 4; ++r) {
      int m = m0 + wm + i * 16 + lk * 4 + r;
      if (m >= M) continue;
      long base = (long)(m & 31) * sb + (long)(m >> 5) * st;
#pragma unroll
      for (int j = 0; j < 4; ++j) {
        int n = n0 + wn + j * 16 + lr;
        out[base + n] = acc[i][j][r] + bias[n];
      }
    }
  }
}

// ---------------- encoder recurrent step ----------------
__global__ __launch_bounds__(256) void k_enc_step(
    const float* __restrict__ gi_all, const float* __restrict__ WhhT,
    const float* __restrict__ bhh, const int* __restrict__ lens,
    const float* __restrict__ h_in, float* __restrict__ h_out,
    float* __restrict__ EO, int s) {
  __shared__ float hs[2048];
  int t = threadIdx.x;
  int j0 = (blockIdx.x & 7) * 64;
  int b0 = (blockIdx.x >> 3) * 4;
  const float4* h4 = (const float4*)(h_in + b0 * 512);
  for (int i = t; i < 512; i += 256) ((float4*)hs)[i] = h4[i];
  __syncthreads();
  int tj = t & 63, tb = t >> 6;
  int j = j0 + tj, b = b0 + tb;
  const float* hr = hs + tb * 512;
  float ar = bhh[j], az = bhh[512 + j], an = bhh[1024 + j];
  for (int k = 0; k < 512; k += 4) {
    float4 hk = *(const float4*)(hr + k);
    const float* w = WhhT + (long)k * 1536;
    ar += hk.x * w[j];        az += hk.x * w[512 + j];  an += hk.x * w[1024 + j];
    ar += hk.y * w[1536 + j]; az += hk.y * w[2048 + j]; an += hk.y * w[2560 + j];
    ar += hk.z * w[3072 + j]; az += hk.z * w[3584 + j]; an += hk.z * w[4096 + j];
    ar += hk.w * w[4608 + j]; az += hk.w * w[5120 + j]; an += hk.w * w[5632 + j];
  }
  const float* gi = gi_all + ((long)s * 32 + b) * 1536;
  float r = 1.f / (1.f + expf(-(gi[j] + ar)));
  float z = 1.f / (1.f + expf(-(gi[512 + j] + az)));
  float n = tanhf(gi[1024 + j] + r * an);
  float hold = hr[j];
  float hnew = (1.f - z) * n + z * hold;
  bool valid = s < lens[b];
  h_out[b * 512 + j] = valid ? hnew : hold;
  EO[((long)b * 128 + s) * 512 + j] = valid ? hnew : 0.f;
}

// ---------------- decoder attention ----------------
__global__ __launch_bounds__(256) void k_dec_att(
    const float* __restrict__ EO, const float* __restrict__ h,
    const int* __restrict__ lens,
    float* __restrict__ ctx, float* __restrict__ attns, int tstep) {
  __shared__ float hsv[512];
  __shared__ float sc[128];
  __shared__ float wred[8];
  int b = blockIdx.x;
  int t = threadIdx.x;
  int lane = t & 63, wave = t >> 6;
  for (int i = t; i < 128; i += 256) ((float4*)hsv)[i] = ((const float4*)(h + b * 512))[i];
  __syncthreads();
  float4 h1 = ((const float4*)hsv)[lane * 2];
  float4 h2 = ((const float4*)hsv)[lane * 2 + 1];
  for (int si = 0; si < 32; ++si) {
    int s = wave * 32 + si;
    const float4* er = (const float4*)(EO + ((long)b * 128 + s) * 512);
    float4 e1 = er[lane * 2], e2 = er[lane * 2 + 1];
    float p = e1.x * h1.x + e1.y * h1.y + e1.z * h1.z + e1.w * h1.w +
              e2.x * h2.x + e2.y * h2.y + e2.z * h2.z + e2.w * h2.w;
#pragma unroll
    for (int off = 32; off > 0; off >>= 1) p += __shfl_down(p, off, 64);
    if (lane == 0) sc[s] = p;
  }
  __syncthreads();
  int len = lens[b];
  float v = (t < 128) ? ((t < len) ? sc[t] : -INFINITY) : -INFINITY;
  float wm = v;
#pragma unroll
  for (int off = 32; off > 0; off >>= 1) wm = fmaxf(wm, __shfl_down(wm, off, 64));
  if (lane == 0) wred[wave] = wm;
  __syncthreads();
  float m = fmaxf(fmaxf(wred[0], wred[1]), fmaxf(wred[2], wred[3]));
  float e = (t < 128 && t < len) ? expf(sc[t] - m) : 0.f;
  float wsum = e;
#pragma unroll
  for (int off = 32; off > 0; off >>= 1) wsum += __shfl_down(wsum, off, 64);
  if (lane == 0) wred[4 + wave] = wsum;
  __syncthreads();
  float ssum = wred[4] + wred[5] + wred[6] + wred[7];
  float aw = e / ssum;
  if (t < 128) {
    sc[t] = aw;
    attns[((long)b * STEPS_ + tstep) * 128 + t] = aw;
  }
  __syncthreads();
  for (int j = t; j < 512; j += 256) {
    float acc = 0.f;
    for (int s = 0; s < 128; ++s) acc += sc[s] * EO[((long)b * 128 + s) * 512 + j];
    ctx[b * 512 + j] = acc;
  }
}

// ---------------- decoder GRU cell ----------------
__global__ __launch_bounds__(256) void k_dec_cell(
    const float* __restrict__ gie, const float* __restrict__ ctx,
    const float* __restrict__ WihT,  // [1024][1536], ctx part rows 512..1023
    const float* __restrict__ WhhT,  // [512][1536]
    const float* __restrict__ bhh,
    const float* __restrict__ h_in, float* __restrict__ h_out, int tstep) {
  __shared__ float hs[2048];
  __shared__ float cs[2048];
  int t = threadIdx.x;
  int j0 = (blockIdx.x & 7) * 64;
  int b0 = (blockIdx.x >> 3) * 4;
  const float4* h4 = (const float4*)(h_in + b0 * 512);
  const float4* c4 = (const float4*)(ctx + b0 * 512);
  for (int i = t; i < 512; i += 256) { ((float4*)hs)[i] = h4[i]; ((float4*)cs)[i] = c4[i]; }
  __syncthreads();
  int tj = t & 63, tb = t >> 6;
  int j = j0 + tj, b = b0 + tb;
  const float* hr = hs + tb * 512;
  const float* cr = cs + tb * 512;
  float ar = bhh[j], az = bhh[512 + j], an = bhh[1024 + j];
  float gr = 0.f, gz = 0.f, gn = 0.f;
  for (int k = 0; k < 512; k += 4) {
    float4 hk = *(const float4*)(hr + k);
    float4 ck = *(const float4*)(cr + k);
    const float* wh = WhhT + (long)k * 1536;
    const float* wc = WihT + (long)(512 + k) * 1536;
    ar += hk.x * wh[j];        az += hk.x * wh[512 + j];  an += hk.x * wh[1024 + j];
    ar += hk.y * wh[1536 + j]; az += hk.y * wh[2048 + j]; an += hk.y * wh[2560 + j];
    ar += hk.z * wh[3072 + j]; az += hk.z * wh[3584 + j]; an += hk.z * wh[4096 + j];
    ar += hk.w * wh[4608 + j]; az += hk.w * wh[5120 + j]; an += hk.w * wh[5632 + j];
    gr += ck.x * wc[j];        gz += ck.x * wc[512 + j];  gn += ck.x * wc[1024 + j];
    gr += ck.y * wc[1536 + j]; gz += ck.y * wc[2048 + j]; gn += ck.y * wc[2560 + j];
    gr += ck.z * wc[3072 + j]; gz += ck.z * wc[3584 + j]; gn += ck.z * wc[4096 + j];
    gr += ck.w * wc[4608 + j]; gz += ck.w * wc[5120 + j]; gn += ck.w * wc[5632 + j];
  }
  const float* gi = gie + ((long)tstep * 32 + b) * 1536;
  float r = 1.f / (1.f + expf(-(gi[j] + gr + ar)));
  float z = 1.f / (1.f + expf(-(gi[512 + j] + gz + az)));
  float n = tanhf(gi[1024 + j] + gn + r * an);
  float hold = hr[j];
  h_out[b * 512 + j] = (1.f - z) * n + z * hold;
}

// ---------------- decoder cc = tanh([hn,ctx] @ Wc.T + bc) ----------------
__global__ __launch_bounds__(256) void k_dec_cc(
    const float* __restrict__ hn, const float* __restrict__ ctx,
    const float* __restrict__ WcT, const float* __restrict__ bc,
    float* __restrict__ ccall, int tstep) {
  __shared__ float hs[2048];
  __shared__ float cs[2048];
  int t = threadIdx.x;
  int i0 = (blockIdx.x & 7) * 64;
  int b0 = (blockIdx.x >> 3) * 4;
  const float4* h4 = (const float4*)(hn + b0 * 512);
  const float4* c4 = (const float4*)(ctx + b0 * 512);
  for (int i = t; i < 512; i += 256) { ((float4*)hs)[i] = h4[i]; ((float4*)cs)[i] = c4[i]; }
  __syncthreads();
  int ti = t & 63, tb = t >> 6;
  int i = i0 + ti, b = b0 + tb;
  const float* hr = hs + tb * 512;
  const float* cr = cs + tb * 512;
  float acc = bc[i];
  for (int k = 0; k < 512; k += 4) {
    float4 hk = *(const float4*)(hr + k);
    float4 ck = *(const float4*)(cr + k);
    const float* w = WcT + (long)k * 512 + i;
    const float* w2 = WcT + (long)(512 + k) * 512 + i;
    acc += hk.x * w[0];    acc += hk.y * w[512];  acc += hk.z * w[1024];  acc += hk.w * w[1536];
    acc += ck.x * w2[0];   acc += ck.y * w2[512]; acc += ck.z * w2[1024]; acc += ck.w * w2[1536];
  }
  ccall[((long)tstep * 32 + b) * 512 + i] = tanhf(acc);
}

extern "C" void kernel_launch(void* const* d_in, const int* in_sizes, int n_in,
                              void* d_out, int out_size, void* d_ws, size_t ws_size,
                              hipStream_t stream) {
  (void)in_sizes; (void)n_in; (void)out_size; (void)ws_size;
  const int*   src   = (const int*)d_in[0];
  const int*   lens  = (const int*)d_in[1];
  const int*   tgt   = (const int*)d_in[2];
  const float* emb_e = (const float*)d_in[3];
  const float* Wih_e = (const float*)d_in[4];
  const float* Whh_e = (const float*)d_in[5];
  const float* bih_e = (const float*)d_in[6];
  const float* bhh_e = (const float*)d_in[7];
  const float* emb_d = (const float*)d_in[8];
  const float* Wih_d = (const float*)d_in[9];
  const float* Whh_d = (const float*)d_in[10];
  const float* bih_d = (const float*)d_in[11];
  const float* bhh_d = (const float*)d_in[12];
  const float* Wc    = (const float*)d_in[13];
  const float* bc    = (const float*)d_in[14];
  const float* Wo    = (const float*)d_in[15];
  const float* bo    = (const float*)d_in[16];

  float* logits = (float*)d_out;
  float* attns  = (float*)d_out + (long)B_ * STEPS_ * V_;

  float* w = (float*)d_ws;
  float* WihT_d = w;                   // 1024 x 1536 (for k_dec_cell ctx part)
  float* WhhT_e = WihT_d + 1572864;    // 512 x 1536
  float* WhhT_d = WhhT_e + 786432;     // 512 x 1536
  float* WcT    = WhhT_d + 786432;     // 1024 x 512
  float* GIe    = WcT + 524288;        // 4096 x 1536
  float* GId    = GIe + 6291456;       // 2016 x 1536
  float* EO     = GId + 3096576;       // 32 x 128 x 512
  float* h0     = EO + 2097152;        // 32 x 512
  float* h1     = h0 + 16384;
  float* ctx    = h1 + 16384;
  float* ccall  = ctx + 16384;         // 2016 x 512
  float* hb[2] = {h0, h1};

  dim3 tb(32, 8);
  k_transpose<<<dim3(1024 / 32, 1536 / 32), tb, 0, stream>>>(Wih_d, WihT_d, 1536, 1024);
  k_transpose<<<dim3(512 / 32, 1536 / 32), tb, 0, stream>>>(Whh_e, WhhT_e, 1536, 512);
  k_transpose<<<dim3(512 / 32, 1536 / 32), tb, 0, stream>>>(Whh_d, WhhT_d, 1536, 512);
  k_transpose<<<dim3(1024 / 32, 512 / 32), tb, 0, stream>>>(Wc, WcT, 512, 1024);

  // GIe[s*32+b][:] = emb_enc[src[b,s]] @ Wih_e^T + bih_e   (B = Wih_e, k-major already)
  k_mfma_gemm<<<dim3(1536 / 128, 4096 / 128), 256, 0, stream>>>(
      nullptr, emb_e, src, 1, Wih_e, 512, bih_e, GIe, 1536L, 32L * 1536L, 4096, 1536, 512);
  // GId[t*32+b][:] = emb_dec[tgt[b,t]] @ Wih_d[:, :512]^T + bih_d  (ldb=1024)
  k_mfma_gemm<<<dim3(1536 / 128, (2016 + 127) / 128), 256, 0, stream>>>(
      nullptr, emb_d, tgt, 2, Wih_d, 1024, bih_d, GId, 1536L, 32L * 1536L, 2016, 1536, 512);

  hipMemsetAsync(h0, 0, 16384 * sizeof(float), stream);

  for (int s = 0; s < S_; ++s) {
    k_enc_step<<<64, 256, 0, stream>>>(GIe, WhhT_e, bhh_e, lens, hb[s & 1], hb[(s + 1) & 1], EO, s);
  }

  for (int t = 0; t < STEPS_; ++t) {
    k_dec_att<<<32, 256, 0, stream>>>(EO, hb[t & 1], lens, ctx, attns, t);
    k_dec_cell<<<64, 256, 0, stream>>>(GId, ctx, WihT_d, WhhT_d, bhh_d, hb[t & 1], hb[(t + 1) & 1], t);
    k_dec_cc<<<64, 256, 0, stream>>>(hb[(t + 1) & 1], ctx, WcT, bc, ccall, t);
  }

  // logits: A = ccall [2016][512], B = Wo [32000][512] (k-major already)
  k_mfma_gemm<<<dim3(V_ / 128, (2016 + 127) / 128), 256, 0, stream>>>(
      ccall, nullptr, nullptr, 0, Wo, 512, bo, logits,
      (long)STEPS_ * V_, (long)V_, 2016, 32000, 512);
}